// Round 4
// baseline (335.509 us; speedup 1.0000x reference)
//
#include <hip/hip_runtime.h>
#include <hip/hip_bf16.h>

// Problem constants
#define SEGS   8
#define DIM    768
#define NVIS   100
#define BATCH  64
#define LTOK   512
#define CHUNK  64      // tokens per reduction block
#define KS     8       // GEMM K-split
#define KLEN   96      // 768 / KS

// ws layout (float element offsets)
#define OFF_CSUM 0                               // [B][S][D] caption seg sums
#define OFF_TSUM (OFF_CSUM + BATCH*SEGS*DIM)     // [B][S][D] trace seg sums
#define OFF_VSUM (OFF_TSUM + BATCH*SEGS*DIM)     // [B][D]    vision sums
#define OFF_CBUF (OFF_VSUM + BATCH*DIM)          // [B][9][D] GEMM accumulators
#define OFF_CCNT (OFF_CBUF + BATCH*9*DIM)        // [B][S] int caption counts
#define OFF_TCNT (OFF_CCNT + BATCH*SEGS)         // [B][S] int trace counts
#define WS_FLOATS (OFF_TCNT + BATCH*SEGS)

// dtype evidence:
//  - inputs f32: round-1 read-as-bf16 produced NaN
//  - output f32: round-2 bf16-packed output gave sqrt(2)*max|ref| shuffle error
// round-3 bug: epilogue used  d = j & (DIM-1)  but DIM=768 is NOT pow2 ->
// scrambled vt indices (output 1 only; output 0 never computes d). Fix: j % DIM.

// ---------------------------------------------------------------------------
// Fused segment-sum reduction.
// grid = 1024: [type(2)][batch(64)][chunk(8)], block = 192 (each thread 4 cols)
// Sorted-mask trick: seg id is block-uniform per token and changes rarely, so
// we accumulate into a running register set and flush on seg change.
// ---------------------------------------------------------------------------
__global__ __launch_bounds__(192) void reduce_kernel(
    const float* __restrict__ vt_feat,
    const int* __restrict__ vt_mask,
    const float* __restrict__ cap_feat,
    const int* __restrict__ cap_mask,
    float* __restrict__ ws)
{
    const int bid  = blockIdx.x;
    const int type = bid >> 9;          // 0 = caption, 1 = trace/vision
    const int b    = (bid >> 3) & 63;
    const int ck   = bid & 7;
    const int tid  = threadIdx.x;       // 0..191, cols [4*tid, 4*tid+3]

    __shared__ int msk[CHUNK];
    __shared__ int scnt[SEGS + 1];
    if (tid < SEGS + 1) scnt[tid] = 0;
    if (tid < CHUNK) {
        const int l = ck * CHUNK + tid;
        int m;
        if (type == 0) m = cap_mask[b * 513 + 1 + l];
        else           m = (l >= NVIS) ? vt_mask[b * 412 + (l - NVIS)] : 0;
        msk[tid] = m;
    }
    __syncthreads();
    if (tid < CHUNK) { const int m = msk[tid]; if (m > 0) atomicAdd(&scnt[m], 1); }

    float acc[SEGS][4];
#pragma unroll
    for (int s = 0; s < SEGS; ++s) { acc[s][0]=0.f; acc[s][1]=0.f; acc[s][2]=0.f; acc[s][3]=0.f; }
    float vacc[4] = {0.f, 0.f, 0.f, 0.f};
    float tmp[4]  = {0.f, 0.f, 0.f, 0.f};
    int cur = 0;

    const float* __restrict__ feat = (type == 0) ? cap_feat : vt_feat;
    const size_t base = (size_t)b * LTOK * DIM + (size_t)tid * 4;

    for (int j = 0; j < CHUNK; ++j) {
        const int l = ck * CHUNK + j;
        const float4 v4 = *reinterpret_cast<const float4*>(feat + base + (size_t)l * DIM);
        if (type == 1 && l < NVIS) {
            vacc[0] += v4.x; vacc[1] += v4.y; vacc[2] += v4.z; vacc[3] += v4.w;
        } else {
            const int m = __builtin_amdgcn_readfirstlane(msk[j]);
            if (m != cur) {
#pragma unroll
                for (int s = 0; s < SEGS; ++s)
                    if (cur == s + 1) {
                        acc[s][0] += tmp[0]; acc[s][1] += tmp[1];
                        acc[s][2] += tmp[2]; acc[s][3] += tmp[3];
                    }
                tmp[0] = 0.f; tmp[1] = 0.f; tmp[2] = 0.f; tmp[3] = 0.f;
                cur = m;
            }
            tmp[0] += v4.x; tmp[1] += v4.y; tmp[2] += v4.z; tmp[3] += v4.w;
        }
    }
#pragma unroll
    for (int s = 0; s < SEGS; ++s)
        if (cur == s + 1) {
            acc[s][0] += tmp[0]; acc[s][1] += tmp[1];
            acc[s][2] += tmp[2]; acc[s][3] += tmp[3];
        }

    __syncthreads();   // counts complete

    float* __restrict__ sums = ws + (type == 0 ? OFF_CSUM : OFF_TSUM) + (size_t)b * SEGS * DIM;
    int*   __restrict__ cnt  = (int*)(ws + (type == 0 ? OFF_CCNT : OFF_TCNT)) + b * SEGS;
    if (tid < SEGS && scnt[tid + 1] > 0) atomicAdd(&cnt[tid], scnt[tid + 1]);
#pragma unroll
    for (int s = 0; s < SEGS; ++s) {
        if (scnt[s + 1] > 0) {
            float* p = &sums[s * DIM + tid * 4];
            atomicAdd(p + 0, acc[s][0]); atomicAdd(p + 1, acc[s][1]);
            atomicAdd(p + 2, acc[s][2]); atomicAdd(p + 3, acc[s][3]);
        }
    }
    if (type == 1 && ck * CHUNK < NVIS) {   // chunks 0,1 hold vision tokens
        float* vs = ws + OFF_VSUM + (size_t)b * DIM + tid * 4;
        atomicAdd(vs + 0, vacc[0]); atomicAdd(vs + 1, vacc[1]);
        atomicAdd(vs + 2, vacc[2]); atomicAdd(vs + 3, vacc[3]);
    }
}

// ---------------------------------------------------------------------------
// vt merge GEMM: per batch, A = [8 seg means ; vision mean] (9 x 768),
// C[r][d] = sum_k A[r][k] * W[k or 768+k][d].  K split 8 ways for occupancy.
// grid = 512 (64 batches x 8 k-chunks), block = 192 (each thread 4 cols)
// ---------------------------------------------------------------------------
__global__ __launch_bounds__(192) void gemm_kernel(
    const float* __restrict__ W,
    float* __restrict__ ws)
{
    const int b   = blockIdx.x >> 3;
    const int kc  = blockIdx.x & 7;
    const int k0  = kc * KLEN;
    const int tid = threadIdx.x;

    __shared__ __align__(16) float As[9][KLEN];
    __shared__ float invc[SEGS];
    if (tid < SEGS) {
        const int c = ((const int*)(ws + OFF_TCNT))[b * SEGS + tid];
        invc[tid] = (c > 0) ? 1.0f / (float)c : 0.0f;
    }
    __syncthreads();
    for (int i = tid; i < 9 * KLEN; i += 192) {
        const int r = i / KLEN, k = i % KLEN;
        float v;
        if (r < SEGS) v = ws[OFF_TSUM + ((size_t)(b * SEGS + r)) * DIM + k0 + k] * invc[r];
        else          v = ws[OFF_VSUM + (size_t)b * DIM + k0 + k] * (1.0f / (float)NVIS);
        As[r][k] = v;
    }
    __syncthreads();

    float acc[9][4];
#pragma unroll
    for (int r = 0; r < 9; ++r) { acc[r][0]=0.f; acc[r][1]=0.f; acc[r][2]=0.f; acc[r][3]=0.f; }

    const float* __restrict__ Wt = W + (size_t)k0 * DIM + tid * 4;
    const float* __restrict__ Wb = W + (size_t)(DIM + k0) * DIM + tid * 4;

    for (int k = 0; k < KLEN; k += 4) {
        float a[9][4];
#pragma unroll
        for (int r = 0; r < 9; ++r) {
            const float4 t = *reinterpret_cast<const float4*>(&As[r][k]);
            a[r][0] = t.x; a[r][1] = t.y; a[r][2] = t.z; a[r][3] = t.w;
        }
#pragma unroll
        for (int u = 0; u < 4; ++u) {
            const float4 wt4 = *reinterpret_cast<const float4*>(Wt + (size_t)(k + u) * DIM);
            const float4 wb4 = *reinterpret_cast<const float4*>(Wb + (size_t)(k + u) * DIM);
            const float wt[4] = {wt4.x, wt4.y, wt4.z, wt4.w};
            const float wb[4] = {wb4.x, wb4.y, wb4.z, wb4.w};
#pragma unroll
            for (int r = 0; r < SEGS; ++r) {
#pragma unroll
                for (int j = 0; j < 4; ++j) acc[r][j] += a[r][u] * wt[j];
            }
#pragma unroll
            for (int j = 0; j < 4; ++j) acc[8][j] += a[8][u] * wb[j];
        }
    }

    float* __restrict__ C = ws + OFF_CBUF + (size_t)b * 9 * DIM + tid * 4;
#pragma unroll
    for (int r = 0; r < 9; ++r) {
        atomicAdd(&C[r * DIM + 0], acc[r][0]);
        atomicAdd(&C[r * DIM + 1], acc[r][1]);
        atomicAdd(&C[r * DIM + 2], acc[r][2]);
        atomicAdd(&C[r * DIM + 3], acc[r][3]);
    }
}

// ---------------------------------------------------------------------------
// Epilogue: caption means (masked) and vt output (add vision row + bias, mask).
// OUTPUT IS FLOAT32.  grid = 3072 x 256 over 786432 outputs.
// ---------------------------------------------------------------------------
__global__ __launch_bounds__(256) void epilogue_kernel(
    const float* __restrict__ bias,
    const float* __restrict__ ws,
    float* __restrict__ out)
{
    const int i = blockIdx.x * 256 + threadIdx.x;
    const int HALF = BATCH * SEGS * DIM;   // 393216
    if (i < HALF) {
        const int b = i / (SEGS * DIM);
        const int s = (i / DIM) & (SEGS - 1);
        const int c = ((const int*)(ws + OFF_CCNT))[b * SEGS + s];
        float v = 0.f;
        if (c > 0) v = ws[OFF_CSUM + i] / (float)c;
        out[i] = v;
    } else {
        const int j = i - HALF;
        const int b = j / (SEGS * DIM);
        const int s = (j / DIM) & (SEGS - 1);   // ok: (j/768) % 8, 8 is pow2
        const int d = j % DIM;                   // FIX: DIM=768 not pow2, & was wrong
        const int c = ((const int*)(ws + OFF_TCNT))[b * SEGS + s];
        float v = 0.f;
        if (c > 0) {
            const float* C = ws + OFF_CBUF + (size_t)b * 9 * DIM;
            v = C[s * DIM + d] + C[8 * DIM + d] + bias[d];
        }
        out[i] = v;
    }
}

extern "C" void kernel_launch(void* const* d_in, const int* in_sizes, int n_in,
                              void* d_out, int out_size, void* d_ws, size_t ws_size,
                              hipStream_t stream) {
    const float* vt_feat  = (const float*)d_in[0];
    const int*   vt_mask  = (const int*)d_in[1];
    const float* cap_feat = (const float*)d_in[2];
    const int*   cap_mask = (const int*)d_in[3];
    const float* W        = (const float*)d_in[4];
    const float* bias     = (const float*)d_in[5];
    float* out = (float*)d_out;
    float* ws = (float*)d_ws;

    hipMemsetAsync(d_ws, 0, (size_t)WS_FLOATS * sizeof(float), stream);
    reduce_kernel<<<1024, 192, 0, stream>>>(vt_feat, vt_mask, cap_feat, cap_mask, ws);
    gemm_kernel<<<512, 192, 0, stream>>>(W, ws);
    epilogue_kernel<<<3072, 256, 0, stream>>>(bias, ws, out);
}

// Round 5
// 306.836 us; speedup vs baseline: 1.0934x; 1.0934x over previous
//
#include <hip/hip_runtime.h>
#include <hip/hip_bf16.h>

// Problem constants
#define SEGS   8
#define DIM    768
#define NVIS   100
#define BATCH  64
#define LTOK   512
#define NCHK   4        // reduction chunks per sequence
#define TPC    128      // tokens per chunk (512/4)
#define KS     8        // GEMM K-split
#define KLEN   96       // 768 / KS

// ws layout (float element offsets) — NO atomics, NO memset: every slot is
// written by construction before it is read.
#define OFF_PCAP  0                                   // [B][NCHK][S][D] caption chunk partials
#define OFF_PTRC  (OFF_PCAP + BATCH*NCHK*SEGS*DIM)    // [B][NCHK][S][D] trace chunk partials
#define OFF_PVIS  (OFF_PTRC + BATCH*NCHK*SEGS*DIM)    // [B][D] vision sums (all vis tokens in chunk 0)
#define OFF_TMEAN (OFF_PVIS + BATCH*DIM)              // [B][9][D] rows 0-7 trace means, row 8 vision mean
#define OFF_PGEM  (OFF_TMEAN + BATCH*9*DIM)           // [KS][B][9][D] GEMM K-split partials
#define OFF_PCCNT (OFF_PGEM + KS*BATCH*9*DIM)         // [B][NCHK][S] int caption chunk counts
#define OFF_PTCNT (OFF_PCCNT + BATCH*NCHK*SEGS)       // [B][NCHK][S] int trace chunk counts
#define OFF_TCNT  (OFF_PTCNT + BATCH*NCHK*SEGS)       // [B][S] int summed trace counts
#define WS_FLOATS (OFF_TCNT + BATCH*SEGS)             // ~7.2M floats = 28.7 MB

// dtype evidence: inputs f32 (round-1 NaN), output f32 (round-2 shuffle sig).
// round-4 evidence: 3.54M global atomicAdds in gemm = 55MB RMW traffic = 93us
// at 6% VALUBusy. This round: zero global atomics anywhere.

// ---------------------------------------------------------------------------
// Segment-sum reduction -> plain-store chunk partials.
// grid = 512: [type(2)][batch(64)][chunk(4)], block = 192 (thread = 4 cols)
// Sorted-mask run trick: seg id is block-uniform per token, changes rarely.
// ---------------------------------------------------------------------------
__global__ __launch_bounds__(192) void reduce_kernel(
    const float* __restrict__ vt_feat,
    const int* __restrict__ vt_mask,
    const float* __restrict__ cap_feat,
    const int* __restrict__ cap_mask,
    float* __restrict__ ws)
{
    const int bid  = blockIdx.x;
    const int type = bid >> 8;          // 0 = caption, 1 = trace/vision
    const int b    = (bid >> 2) & 63;
    const int ck   = bid & 3;
    const int tid  = threadIdx.x;       // 0..191, cols [4*tid, 4*tid+3]

    __shared__ int msk[TPC];
    __shared__ int scnt[SEGS + 1];
    if (tid < SEGS + 1) scnt[tid] = 0;
    if (tid < TPC) {
        const int l = ck * TPC + tid;
        int m;
        if (type == 0) m = cap_mask[b * 513 + 1 + l];
        else           m = (l >= NVIS) ? vt_mask[b * 412 + (l - NVIS)] : 0;
        msk[tid] = m;
    }
    __syncthreads();
    if (tid < TPC) { const int m = msk[tid]; if (m > 0) atomicAdd(&scnt[m], 1); }  // LDS atomic only

    float acc[SEGS][4];
#pragma unroll
    for (int s = 0; s < SEGS; ++s) { acc[s][0]=0.f; acc[s][1]=0.f; acc[s][2]=0.f; acc[s][3]=0.f; }
    float vacc[4] = {0.f, 0.f, 0.f, 0.f};
    float tmp[4]  = {0.f, 0.f, 0.f, 0.f};
    int cur = 0;

    const float* __restrict__ feat = (type == 0) ? cap_feat : vt_feat;
    const size_t base = (size_t)b * LTOK * DIM + (size_t)tid * 4;

    for (int j = 0; j < TPC; ++j) {
        const int l = ck * TPC + j;
        const float4 v4 = *reinterpret_cast<const float4*>(feat + base + (size_t)l * DIM);
        if (type == 1 && l < NVIS) {   // vision tokens: l<100, all in chunk 0
            vacc[0] += v4.x; vacc[1] += v4.y; vacc[2] += v4.z; vacc[3] += v4.w;
        } else {
            const int m = __builtin_amdgcn_readfirstlane(msk[j]);
            if (m != cur) {
#pragma unroll
                for (int s = 0; s < SEGS; ++s)
                    if (cur == s + 1) {
                        acc[s][0] += tmp[0]; acc[s][1] += tmp[1];
                        acc[s][2] += tmp[2]; acc[s][3] += tmp[3];
                    }
                tmp[0] = 0.f; tmp[1] = 0.f; tmp[2] = 0.f; tmp[3] = 0.f;
                cur = m;
            }
            tmp[0] += v4.x; tmp[1] += v4.y; tmp[2] += v4.z; tmp[3] += v4.w;
        }
    }
#pragma unroll
    for (int s = 0; s < SEGS; ++s)
        if (cur == s + 1) {
            acc[s][0] += tmp[0]; acc[s][1] += tmp[1];
            acc[s][2] += tmp[2]; acc[s][3] += tmp[3];
        }

    __syncthreads();   // counts complete

    // Plain stores: all SEGS slots written (zeros where seg absent).
    float* __restrict__ pbase = ws + (type == 0 ? OFF_PCAP : OFF_PTRC)
                              + ((size_t)(b * NCHK + ck) * SEGS) * DIM;
#pragma unroll
    for (int s = 0; s < SEGS; ++s) {
        reinterpret_cast<float4*>(pbase + s * DIM)[tid] =
            make_float4(acc[s][0], acc[s][1], acc[s][2], acc[s][3]);
    }
    int* __restrict__ cbase = (int*)(ws + (type == 0 ? OFF_PCCNT : OFF_PTCNT))
                            + (b * NCHK + ck) * SEGS;
    if (tid < SEGS) cbase[tid] = scnt[tid + 1];
    if (type == 1 && ck == 0) {
        reinterpret_cast<float4*>(ws + OFF_PVIS + (size_t)b * DIM)[tid] =
            make_float4(vacc[0], vacc[1], vacc[2], vacc[3]);
    }
}

// ---------------------------------------------------------------------------
// Combine 1: fold chunk partials. Writes caption OUTPUT directly, trace means
// (pre-divided) + vision mean into TMEAN, trace counts into TCNT.
// grid = 3264 x 256 over 835584 elements.
// ---------------------------------------------------------------------------
__global__ __launch_bounds__(256) void combine1_kernel(
    const float* __restrict__ ws_c, float* __restrict__ ws,
    float* __restrict__ out)
{
    const int i = blockIdx.x * 256 + threadIdx.x;
    const int CAPN = BATCH * SEGS * DIM;   // 393216
    if (i < CAPN) {
        const int b = i / (SEGS * DIM);
        const int r = i % (SEGS * DIM);
        const int s = r / DIM, d = r % DIM;
        float sum = 0.f; int c = 0;
#pragma unroll
        for (int ck = 0; ck < NCHK; ++ck) {
            sum += ws_c[OFF_PCAP + ((size_t)((b * NCHK + ck) * SEGS + s)) * DIM + d];
            c   += ((const int*)(ws_c + OFF_PCCNT))[(b * NCHK + ck) * SEGS + s];
        }
        out[i] = (c > 0) ? sum / (float)c : 0.f;
    } else if (i < 2 * CAPN) {
        const int j = i - CAPN;
        const int b = j / (SEGS * DIM);
        const int r = j % (SEGS * DIM);
        const int s = r / DIM, d = r % DIM;
        float sum = 0.f; int c = 0;
#pragma unroll
        for (int ck = 0; ck < NCHK; ++ck) {
            sum += ws_c[OFF_PTRC + ((size_t)((b * NCHK + ck) * SEGS + s)) * DIM + d];
            c   += ((const int*)(ws_c + OFF_PTCNT))[(b * NCHK + ck) * SEGS + s];
        }
        ws[OFF_TMEAN + ((size_t)(b * 9 + s)) * DIM + d] = (c > 0) ? sum / (float)c : 0.f;
        if (d == 0) ((int*)(ws + OFF_TCNT))[b * SEGS + s] = c;
    } else {
        const int j = i - 2 * CAPN;
        const int b = j / DIM, d = j % DIM;
        ws[OFF_TMEAN + ((size_t)(b * 9 + 8)) * DIM + d] =
            ws_c[OFF_PVIS + (size_t)b * DIM + d] * (1.0f / (float)NVIS);
    }
}

// ---------------------------------------------------------------------------
// vt merge GEMM: A = TMEAN[b] (9 x 768, already divided), rows 0-7 x Wtop,
// row 8 x Wbot. K split 8 ways; partials PLAIN-stored (round-4 atomics: 93us).
// grid = 512 (64 batches x 8 k-chunks), block = 192 (thread = 4 cols)
// ---------------------------------------------------------------------------
__global__ __launch_bounds__(192) void gemm_kernel(
    const float* __restrict__ W,
    const float* __restrict__ ws_c,
    float* __restrict__ ws)
{
    const int b   = blockIdx.x >> 3;
    const int kc  = blockIdx.x & 7;
    const int k0  = kc * KLEN;
    const int tid = threadIdx.x;

    __shared__ __align__(16) float As[9][KLEN];
    for (int i = tid; i < 9 * KLEN; i += 192) {
        const int r = i / KLEN, k = i % KLEN;
        As[r][k] = ws_c[OFF_TMEAN + ((size_t)(b * 9 + r)) * DIM + k0 + k];
    }
    __syncthreads();

    float acc[9][4];
#pragma unroll
    for (int r = 0; r < 9; ++r) { acc[r][0]=0.f; acc[r][1]=0.f; acc[r][2]=0.f; acc[r][3]=0.f; }

    const float* __restrict__ Wt = W + (size_t)k0 * DIM + tid * 4;
    const float* __restrict__ Wb = W + (size_t)(DIM + k0) * DIM + tid * 4;

    for (int k = 0; k < KLEN; k += 4) {
        float a[9][4];
#pragma unroll
        for (int r = 0; r < 9; ++r) {
            const float4 t = *reinterpret_cast<const float4*>(&As[r][k]);
            a[r][0] = t.x; a[r][1] = t.y; a[r][2] = t.z; a[r][3] = t.w;
        }
#pragma unroll
        for (int u = 0; u < 4; ++u) {
            const float4 wt4 = *reinterpret_cast<const float4*>(Wt + (size_t)(k + u) * DIM);
            const float4 wb4 = *reinterpret_cast<const float4*>(Wb + (size_t)(k + u) * DIM);
            const float wt[4] = {wt4.x, wt4.y, wt4.z, wt4.w};
            const float wb[4] = {wb4.x, wb4.y, wb4.z, wb4.w};
#pragma unroll
            for (int r = 0; r < SEGS; ++r) {
#pragma unroll
                for (int j = 0; j < 4; ++j) acc[r][j] += a[r][u] * wt[j];
            }
#pragma unroll
            for (int j = 0; j < 4; ++j) acc[8][j] += a[8][u] * wb[j];
        }
    }

    float* __restrict__ P = ws + OFF_PGEM + ((size_t)(kc * BATCH + b) * 9) * DIM;
#pragma unroll
    for (int r = 0; r < 9; ++r)
        reinterpret_cast<float4*>(P + r * DIM)[tid] =
            make_float4(acc[r][0], acc[r][1], acc[r][2], acc[r][3]);
}

// ---------------------------------------------------------------------------
// Combine 2: fold 8 GEMM K-partials (seg row + vision row) + bias, apply
// presence mask, write vt OUTPUT.  grid = 1536 x 256 over 393216 elements.
// ---------------------------------------------------------------------------
__global__ __launch_bounds__(256) void combine2_kernel(
    const float* __restrict__ bias,
    const float* __restrict__ ws_c,
    float* __restrict__ out)
{
    const int j = blockIdx.x * 256 + threadIdx.x;
    const int HALF = BATCH * SEGS * DIM;   // 393216
    const int b = j / (SEGS * DIM);
    const int r = j % (SEGS * DIM);
    const int s = r / DIM, d = r % DIM;    // DIM=768 not pow2: use / and %
    const int c = ((const int*)(ws_c + OFF_TCNT))[b * SEGS + s];
    float v = 0.f;
    if (c > 0) {
        float sum = bias[d];
#pragma unroll
        for (int kc = 0; kc < KS; ++kc) {
            const float* P = ws_c + OFF_PGEM + ((size_t)(kc * BATCH + b) * 9) * DIM;
            sum += P[s * DIM + d] + P[8 * DIM + d];
        }
        v = sum;
    }
    out[HALF + j] = v;
}

extern "C" void kernel_launch(void* const* d_in, const int* in_sizes, int n_in,
                              void* d_out, int out_size, void* d_ws, size_t ws_size,
                              hipStream_t stream) {
    const float* vt_feat  = (const float*)d_in[0];
    const int*   vt_mask  = (const int*)d_in[1];
    const float* cap_feat = (const float*)d_in[2];
    const int*   cap_mask = (const int*)d_in[3];
    const float* W        = (const float*)d_in[4];
    const float* bias     = (const float*)d_in[5];
    float* out = (float*)d_out;
    float* ws = (float*)d_ws;

    // No memset: every ws slot is plain-stored before it is read.
    reduce_kernel  <<<512, 192, 0, stream>>>(vt_feat, vt_mask, cap_feat, cap_mask, ws);
    combine1_kernel<<<3264, 256, 0, stream>>>(ws, ws, out);
    gemm_kernel    <<<512, 192, 0, stream>>>(W, ws, ws);
    combine2_kernel<<<1536, 256, 0, stream>>>(bias, ws, out);
}

// Round 6
// 283.881 us; speedup vs baseline: 1.1819x; 1.0809x over previous
//
#include <hip/hip_runtime.h>
#include <hip/hip_bf16.h>

// Problem constants
#define SEGS   8
#define DIM    768
#define NVIS   100
#define BATCH  64
#define LTOK   512
#define NCHK   8        // reduction chunks per sequence (r5: 4 -> 8 for occupancy)
#define TPC    64       // tokens per chunk (512/8)
#define KS     8        // GEMM K-split
#define KLEN   96       // 768 / KS

// ws layout (float element offsets). PGEM overlays the chunk-partial region:
// combine1 fully consumes PCAP/PTRC/PVIS/counts before gemm writes PGEM
// (stream-ordered), so the regions can alias. Total ~6.8M floats = 27 MB.
#define OFF_PCAP  0                                   // [B][NCHK][S][D] caption chunk partials
#define OFF_PTRC  (OFF_PCAP + BATCH*NCHK*SEGS*DIM)    // [B][NCHK][S][D] trace chunk partials
#define OFF_PVIS  (OFF_PTRC + BATCH*NCHK*SEGS*DIM)    // [B][2][D] vision sums (chunks 0,1 only)
#define OFF_PCCNT (OFF_PVIS + BATCH*2*DIM)            // [B][NCHK][S] int caption chunk counts
#define OFF_PTCNT (OFF_PCCNT + BATCH*NCHK*SEGS)       // [B][NCHK][S] int trace chunk counts
#define OFF_TMEAN (OFF_PTCNT + BATCH*NCHK*SEGS)       // [B][9][D] trace means + vision mean (row 8)
#define OFF_TCNT  (OFF_TMEAN + BATCH*9*DIM)           // [B][S] int summed trace counts
#define OFF_PGEM  0                                   // [KS][B][9][D] GEMM partials (overlay)

// Evidence log: inputs f32 (r1 NaN sig), output f32 (r2 shuffle sig).
// r4: 3.5M global atomics = 93us gemm -> plain-store partials.
// r5: reduce 112us @ 12.6% HBM / 11% VALU / 15% occ = latency-bound;
//     fix = 2x grid + 4-deep load batching for memory-level parallelism.

// ---------------------------------------------------------------------------
// Segment-sum reduction -> plain-store chunk partials.
// grid = 1024: [type(2)][batch(64)][chunk(8)], block = 192 (thread = 4 cols)
// Sorted-mask run trick: seg id is block-uniform per token, changes rarely.
// 4 tokens' loads issued before any mask logic -> 4 loads in flight per wave.
// ---------------------------------------------------------------------------
__global__ __launch_bounds__(192) void reduce_kernel(
    const float* __restrict__ vt_feat,
    const int* __restrict__ vt_mask,
    const float* __restrict__ cap_feat,
    const int* __restrict__ cap_mask,
    float* __restrict__ ws)
{
    const int bid  = blockIdx.x;
    const int type = bid >> 9;          // 0 = caption, 1 = trace/vision
    const int b    = (bid >> 3) & 63;
    const int ck   = bid & 7;
    const int tid  = threadIdx.x;       // 0..191, cols [4*tid, 4*tid+3]

    __shared__ __align__(16) int msk[TPC];
    __shared__ int scnt[SEGS + 1];
    if (tid < SEGS + 1) scnt[tid] = 0;
    if (tid < TPC) {
        const int l = ck * TPC + tid;
        int m;
        if (type == 0) m = cap_mask[b * 513 + 1 + l];
        else           m = (l >= NVIS) ? vt_mask[b * 412 + (l - NVIS)] : 0;
        msk[tid] = m;
    }
    __syncthreads();
    if (tid < TPC) { const int m = msk[tid]; if (m > 0) atomicAdd(&scnt[m], 1); }  // LDS atomic only

    float acc[SEGS][4];
#pragma unroll
    for (int s = 0; s < SEGS; ++s) { acc[s][0]=0.f; acc[s][1]=0.f; acc[s][2]=0.f; acc[s][3]=0.f; }
    float vacc[4] = {0.f, 0.f, 0.f, 0.f};
    float tmp[4]  = {0.f, 0.f, 0.f, 0.f};
    int cur = 0;

    const float* __restrict__ feat = (type == 0) ? cap_feat : vt_feat;
    const size_t base = (size_t)b * LTOK * DIM + (size_t)tid * 4;

    for (int j = 0; j < TPC; j += 4) {
        // Batch 4 independent global loads BEFORE any dependent mask logic.
        const float* p = feat + base + (size_t)(ck * TPC + j) * DIM;
        float4 v[4];
#pragma unroll
        for (int u = 0; u < 4; ++u)
            v[u] = *reinterpret_cast<const float4*>(p + (size_t)u * DIM);
        const int4 m4 = *reinterpret_cast<const int4*>(&msk[j]);
        const int mm[4] = {m4.x, m4.y, m4.z, m4.w};
#pragma unroll
        for (int u = 0; u < 4; ++u) {
            const int l = ck * TPC + j + u;
            if (type == 1 && l < NVIS) {
                vacc[0] += v[u].x; vacc[1] += v[u].y; vacc[2] += v[u].z; vacc[3] += v[u].w;
            } else {
                const int m = __builtin_amdgcn_readfirstlane(mm[u]);
                if (m != cur) {
#pragma unroll
                    for (int s = 0; s < SEGS; ++s)
                        if (cur == s + 1) {
                            acc[s][0] += tmp[0]; acc[s][1] += tmp[1];
                            acc[s][2] += tmp[2]; acc[s][3] += tmp[3];
                        }
                    tmp[0] = 0.f; tmp[1] = 0.f; tmp[2] = 0.f; tmp[3] = 0.f;
                    cur = m;
                }
                tmp[0] += v[u].x; tmp[1] += v[u].y; tmp[2] += v[u].z; tmp[3] += v[u].w;
            }
        }
    }
#pragma unroll
    for (int s = 0; s < SEGS; ++s)
        if (cur == s + 1) {
            acc[s][0] += tmp[0]; acc[s][1] += tmp[1];
            acc[s][2] += tmp[2]; acc[s][3] += tmp[3];
        }

    __syncthreads();   // counts complete

    // Plain stores: all SEGS slots written (zeros where seg absent).
    float* __restrict__ pbase = ws + (type == 0 ? OFF_PCAP : OFF_PTRC)
                              + ((size_t)(b * NCHK + ck) * SEGS) * DIM;
#pragma unroll
    for (int s = 0; s < SEGS; ++s) {
        reinterpret_cast<float4*>(pbase + s * DIM)[tid] =
            make_float4(acc[s][0], acc[s][1], acc[s][2], acc[s][3]);
    }
    int* __restrict__ cbase = (int*)(ws + (type == 0 ? OFF_PCCNT : OFF_PTCNT))
                            + (b * NCHK + ck) * SEGS;
    if (tid < SEGS) cbase[tid] = scnt[tid + 1];
    if (type == 1 && ck < 2) {   // vision tokens l<100 live in chunks 0,1
        reinterpret_cast<float4*>(ws + OFF_PVIS + (size_t)(b * 2 + ck) * DIM)[tid] =
            make_float4(vacc[0], vacc[1], vacc[2], vacc[3]);
    }
}

// ---------------------------------------------------------------------------
// Combine 1: fold chunk partials. Writes caption OUTPUT directly, trace means
// (pre-divided) + vision mean into TMEAN, trace counts into TCNT.
// grid = 3264 x 256 over 835584 elements.
// ---------------------------------------------------------------------------
__global__ __launch_bounds__(256) void combine1_kernel(
    const float* __restrict__ ws_c, float* __restrict__ ws,
    float* __restrict__ out)
{
    const int i = blockIdx.x * 256 + threadIdx.x;
    const int CAPN = BATCH * SEGS * DIM;   // 393216
    if (i < CAPN) {
        const int b = i / (SEGS * DIM);
        const int r = i % (SEGS * DIM);
        const int s = r / DIM, d = r % DIM;
        float sum = 0.f; int c = 0;
#pragma unroll
        for (int ck = 0; ck < NCHK; ++ck) {
            sum += ws_c[OFF_PCAP + ((size_t)((b * NCHK + ck) * SEGS + s)) * DIM + d];
            c   += ((const int*)(ws_c + OFF_PCCNT))[(b * NCHK + ck) * SEGS + s];
        }
        out[i] = (c > 0) ? sum / (float)c : 0.f;
    } else if (i < 2 * CAPN) {
        const int j = i - CAPN;
        const int b = j / (SEGS * DIM);
        const int r = j % (SEGS * DIM);
        const int s = r / DIM, d = r % DIM;
        float sum = 0.f; int c = 0;
#pragma unroll
        for (int ck = 0; ck < NCHK; ++ck) {
            sum += ws_c[OFF_PTRC + ((size_t)((b * NCHK + ck) * SEGS + s)) * DIM + d];
            c   += ((const int*)(ws_c + OFF_PTCNT))[(b * NCHK + ck) * SEGS + s];
        }
        ws[OFF_TMEAN + ((size_t)(b * 9 + s)) * DIM + d] = (c > 0) ? sum / (float)c : 0.f;
        if (d == 0) ((int*)(ws + OFF_TCNT))[b * SEGS + s] = c;
    } else {
        const int j = i - 2 * CAPN;
        const int b = j / DIM, d = j % DIM;
        ws[OFF_TMEAN + ((size_t)(b * 9 + 8)) * DIM + d] =
            (ws_c[OFF_PVIS + (size_t)(b * 2 + 0) * DIM + d] +
             ws_c[OFF_PVIS + (size_t)(b * 2 + 1) * DIM + d]) * (1.0f / (float)NVIS);
    }
}

// ---------------------------------------------------------------------------
// vt merge GEMM: A = TMEAN[b] (9 x 768, already divided), rows 0-7 x Wtop,
// row 8 x Wbot. K split 8 ways; partials PLAIN-stored into PGEM overlay.
// grid = 512 (64 batches x 8 k-chunks), block = 192 (thread = 4 cols)
// ---------------------------------------------------------------------------
__global__ __launch_bounds__(192) void gemm_kernel(
    const float* __restrict__ W,
    const float* __restrict__ ws_c,
    float* __restrict__ ws)
{
    const int b   = blockIdx.x >> 3;
    const int kc  = blockIdx.x & 7;
    const int k0  = kc * KLEN;
    const int tid = threadIdx.x;

    __shared__ __align__(16) float As[9][KLEN];
    for (int i = tid; i < 9 * KLEN; i += 192) {
        const int r = i / KLEN, k = i % KLEN;
        As[r][k] = ws_c[OFF_TMEAN + ((size_t)(b * 9 + r)) * DIM + k0 + k];
    }
    __syncthreads();

    float acc[9][4];
#pragma unroll
    for (int r = 0; r < 9; ++r) { acc[r][0]=0.f; acc[r][1]=0.f; acc[r][2]=0.f; acc[r][3]=0.f; }

    const float* __restrict__ Wt = W + (size_t)k0 * DIM + tid * 4;
    const float* __restrict__ Wb = W + (size_t)(DIM + k0) * DIM + tid * 4;

    for (int k = 0; k < KLEN; k += 4) {
        float a[9][4];
#pragma unroll
        for (int r = 0; r < 9; ++r) {
            const float4 t = *reinterpret_cast<const float4*>(&As[r][k]);
            a[r][0] = t.x; a[r][1] = t.y; a[r][2] = t.z; a[r][3] = t.w;
        }
#pragma unroll
        for (int u = 0; u < 4; ++u) {
            const float4 wt4 = *reinterpret_cast<const float4*>(Wt + (size_t)(k + u) * DIM);
            const float4 wb4 = *reinterpret_cast<const float4*>(Wb + (size_t)(k + u) * DIM);
            const float wt[4] = {wt4.x, wt4.y, wt4.z, wt4.w};
            const float wb[4] = {wb4.x, wb4.y, wb4.z, wb4.w};
#pragma unroll
            for (int r = 0; r < SEGS; ++r) {
#pragma unroll
                for (int j = 0; j < 4; ++j) acc[r][j] += a[r][u] * wt[j];
            }
#pragma unroll
            for (int j = 0; j < 4; ++j) acc[8][j] += a[8][u] * wb[j];
        }
    }

    float* __restrict__ P = ws + OFF_PGEM + ((size_t)(kc * BATCH + b) * 9) * DIM;
#pragma unroll
    for (int r = 0; r < 9; ++r)
        reinterpret_cast<float4*>(P + r * DIM)[tid] =
            make_float4(acc[r][0], acc[r][1], acc[r][2], acc[r][3]);
}

// ---------------------------------------------------------------------------
// Combine 2: fold 8 GEMM K-partials (seg row + vision row) + bias, apply
// presence mask, write vt OUTPUT.  grid = 1536 x 256 over 393216 elements.
// ---------------------------------------------------------------------------
__global__ __launch_bounds__(256) void combine2_kernel(
    const float* __restrict__ bias,
    const float* __restrict__ ws_c,
    float* __restrict__ out)
{
    const int j = blockIdx.x * 256 + threadIdx.x;
    const int HALF = BATCH * SEGS * DIM;   // 393216
    const int b = j / (SEGS * DIM);
    const int r = j % (SEGS * DIM);
    const int s = r / DIM, d = r % DIM;    // DIM=768 not pow2: use / and %
    const int c = ((const int*)(ws_c + OFF_TCNT))[b * SEGS + s];
    float v = 0.f;
    if (c > 0) {
        float sum = bias[d];
#pragma unroll
        for (int kc = 0; kc < KS; ++kc) {
            const float* P = ws_c + OFF_PGEM + ((size_t)(kc * BATCH + b) * 9) * DIM;
            sum += P[s * DIM + d] + P[8 * DIM + d];
        }
        v = sum;
    }
    out[HALF + j] = v;
}

extern "C" void kernel_launch(void* const* d_in, const int* in_sizes, int n_in,
                              void* d_out, int out_size, void* d_ws, size_t ws_size,
                              hipStream_t stream) {
    const float* vt_feat  = (const float*)d_in[0];
    const int*   vt_mask  = (const int*)d_in[1];
    const float* cap_feat = (const float*)d_in[2];
    const int*   cap_mask = (const int*)d_in[3];
    const float* W        = (const float*)d_in[4];
    const float* bias     = (const float*)d_in[5];
    float* out = (float*)d_out;
    float* ws = (float*)d_ws;

    // No memset: every ws slot is plain-stored before it is read.
    reduce_kernel  <<<1024, 192, 0, stream>>>(vt_feat, vt_mask, cap_feat, cap_mask, ws);
    combine1_kernel<<<3264, 256, 0, stream>>>(ws, ws, out);
    gemm_kernel    <<<512, 192, 0, stream>>>(W, ws, ws);
    combine2_kernel<<<1536, 256, 0, stream>>>(bias, ws, out);
}